// Round 1
// 125.073 us; speedup vs baseline: 1.0832x; 1.0832x over previous
//
#include <hip/hip_runtime.h>

#define T_SEQ 2048
#define C_DIM 128
#define S_QK 0.08838834764831845f

typedef __attribute__((ext_vector_type(8))) short bf16x8;
typedef __attribute__((ext_vector_type(4))) float f32x4;

// ---- workspace layout (bytes) ----
// qw  bf16 [8][2048][128]            @ 0         (4,194,304)
// kw  bf16 [8][2048][128]            @ 4194304   (4,194,304)
// vw  bf16 [8][128][2048] (V^T)      @ 8388608   (4,194,304)
// Opart f32 [8*72][64][128]          @ 12582912  (18,874,368)
// ml  float2 [8*72][64]              @ 31457280  (294,912)
#define OPART_OFF 12582912UL
#define ML_OFF    31457280UL

// async global->LDS, 16B per lane; LDS dest is wave-uniform base + lane*16
#define GLOAD_LDS16(gp, lp)                                          \
    __builtin_amdgcn_global_load_lds(                                \
        (const __attribute__((address_space(1))) void*)(gp),         \
        (__attribute__((address_space(3))) void*)(lp), 16, 0, 0)

__device__ __forceinline__ unsigned short f2bf(float f) {
    union { float f; unsigned int u; } v; v.f = f;
    unsigned int r = v.u + 0x7FFFu + ((v.u >> 16) & 1u);
    return (unsigned short)(r >> 16);
}

// compact chunk-slot base within a batch, for qt>=8 (chunks of 8 key-tiles)
__device__ __forceinline__ int chunk_base(int qt) {
    int g = qt >> 3;                       // 1,2,3
    if (g == 1) return (qt - 8) * 2;
    if (g == 2) return 16 + (qt - 16) * 3;
    return 40 + (qt - 24) * 4;             // total 72 per batch
}

// ---------------------------------------------------------------------------
// proj (prep fused): one of q|k|vT = (bf16(x)) @ (bf16(W))^T.
// Stages f32 x and W, converts to bf16 during LDS staging (scale folded into
// Wq). grid (256 row-tiles, 3), block 256.
// ---------------------------------------------------------------------------
__global__ __launch_bounds__(256) void proj_kernel(
    const float* __restrict__ x,
    const float* __restrict__ Wk, const float* __restrict__ Wq,
    const float* __restrict__ Wv,
    unsigned short* __restrict__ qo, unsigned short* __restrict__ ko,
    unsigned short* __restrict__ vto)
{
    const int rt = blockIdx.x;             // 64-row tile over B*T
    const int z  = blockIdx.y;             // 0=q, 1=k, 2=v(transposed)
    const int tid  = threadIdx.x;
    const int lane = tid & 63;
    const int w    = tid >> 6;
    const int n16  = lane & 15;
    const int quad = lane >> 4;

    __shared__ __align__(16) unsigned short Wl[128 * 136];   // 34816 B
    __shared__ __align__(16) unsigned short Xl[9216];        // 18432 B

    const float* Wsrc = (z == 0 ? Wq : z == 1 ? Wk : Wv);
    const float wscale = (z == 0) ? S_QK : 1.0f;
    #pragma unroll
    for (int i = 0; i < 16; ++i) {
        int e = (tid + i * 256) * 4;       // 16384 f32, 4 per op
        int r = e >> 7, c = e & 127;
        float4 v = *reinterpret_cast<const float4*>(Wsrc + e);
        ushort4 o4;
        o4.x = f2bf(v.x * wscale); o4.y = f2bf(v.y * wscale);
        o4.z = f2bf(v.z * wscale); o4.w = f2bf(v.w * wscale);
        *reinterpret_cast<ushort4*>(&Wl[r * 136 + c]) = o4;
    }
    const float* xrow = x + (size_t)rt * 64 * C_DIM;
    #pragma unroll
    for (int i = 0; i < 8; ++i) {
        int e = (tid + i * 256) * 4;       // 8192 f32
        int r = e >> 7, c = e & 127;
        float4 v = *reinterpret_cast<const float4*>(xrow + e);
        ushort4 o4;
        o4.x = f2bf(v.x); o4.y = f2bf(v.y);
        o4.z = f2bf(v.z); o4.w = f2bf(v.w);
        *reinterpret_cast<ushort4*>(&Xl[r * 136 + c]) = o4;
    }
    __syncthreads();

    const int arow = w * 16 + n16;
    bf16x8 afr[4];
    #pragma unroll
    for (int kk = 0; kk < 4; ++kk)
        afr[kk] = *reinterpret_cast<const bf16x8*>(&Xl[arow * 136 + kk * 32 + quad * 8]);

    f32x4 acc[8];
    #pragma unroll
    for (int nt = 0; nt < 8; ++nt) acc[nt] = (f32x4){0.f, 0.f, 0.f, 0.f};
    #pragma unroll
    for (int kk = 0; kk < 4; ++kk)
        #pragma unroll
        for (int nt = 0; nt < 8; ++nt) {
            bf16x8 bfr = *reinterpret_cast<const bf16x8*>(
                &Wl[(nt * 16 + n16) * 136 + kk * 32 + quad * 8]);
            acc[nt] = __builtin_amdgcn_mfma_f32_16x16x32_bf16(afr[kk], bfr, acc[nt], 0, 0, 0);
        }

    const int trow_base = w * 16 + quad * 4;
    __syncthreads();                       // all waves done reading Xl
    if (z < 2) {
        #pragma unroll
        for (int nt = 0; nt < 8; ++nt)
            #pragma unroll
            for (int r = 0; r < 4; ++r)
                Xl[(trow_base + r) * 136 + nt * 16 + n16] = f2bf(acc[nt][r]);
        __syncthreads();
        unsigned short* dst = (z == 0 ? qo : ko) + (size_t)rt * 64 * C_DIM;
        #pragma unroll
        for (int i = 0; i < 4; ++i) {
            int e = (tid + i * 256) * 8;
            int r = e >> 7, c = e & 127;
            *reinterpret_cast<uint4*>(dst + e) =
                *reinterpret_cast<const uint4*>(&Xl[r * 136 + c]);
        }
    } else {
        // transpose v tile: vT[d][t_local], row stride 72
        const int b  = rt >> 5;
        const int qt = rt & 31;
        #pragma unroll
        for (int nt = 0; nt < 8; ++nt)
            #pragma unroll
            for (int r = 0; r < 4; ++r)
                Xl[(nt * 16 + n16) * 72 + trow_base + r] = f2bf(acc[nt][r]);
        __syncthreads();
        unsigned short* dst = vto + (size_t)b * C_DIM * T_SEQ + (size_t)qt * 64;
        #pragma unroll
        for (int i = 0; i < 4; ++i) {
            int e = tid + i * 256;
            int d = e >> 3, cv = (e & 7) * 8;
            *reinterpret_cast<uint4*>(dst + (size_t)d * T_SEQ + cv) =
                *reinterpret_cast<const uint4*>(&Xl[d * 72 + cv]);
        }
    }
}

// ---------------------------------------------------------------------------
// attn pass 1: split-K flash attention, software-pipelined staging.
// grid 1024 linear; decode b = lin&7 so one batch maps to one XCD (L2
// affinity for K/V). Double-buffered K/V in LDS via global_load_lds width 16;
// LDS dest is linear, so the bank-swizzle (chunk ^= row&7) is applied on the
// GLOBAL source address and undone on the ds_read side (same involution).
// Counted waits: each STAGE = 8 wave vmem ops (4 K + 4 V), so steady-state
// wait is vmcnt(8) (current tile done, next tile still in flight).
// ---------------------------------------------------------------------------
__device__ __forceinline__ void stage_tile(
    const char* ksb, const char* vsb,
    unsigned short* klbuf, unsigned short* vlbuf, int tid, int w)
{
    #pragma unroll
    for (int it = 0; it < 4; ++it) {                 // K: 64 rows x 16 chunks
        const int L = it * 256 + tid;
        const int r = L >> 4, c = L & 15;
        GLOAD_LDS16(ksb + r * 256 + ((c ^ (r & 7)) << 4),
                    klbuf + (size_t)(it * 256 + w * 64) * 8);
    }
    #pragma unroll
    for (int it = 0; it < 4; ++it) {                 // V^T: 128 rows x 8 chunks
        const int L = it * 256 + tid;
        const int r = L >> 3, c = L & 7;
        GLOAD_LDS16(vsb + (size_t)r * (T_SEQ * 2) + ((c ^ (r & 7)) << 4),
                    vlbuf + (size_t)(it * 256 + w * 64) * 8);
    }
}

__global__ __launch_bounds__(256) void attn_kernel(
    const unsigned short* __restrict__ qb,
    const unsigned short* __restrict__ kb,
    const unsigned short* __restrict__ vtb,
    float* __restrict__ opart, float2* __restrict__ mlbuf,
    float* __restrict__ out)
{
    const int lin   = blockIdx.x;
    const int b     = lin & 7;             // batch -> XCD affinity
    const int rest  = lin >> 3;
    const int qt    = rest & 31;
    const int chunk = rest >> 5;
    if (chunk * 8 > qt) return;

    const int tid  = threadIdx.x;
    const int lane = tid & 63;
    const int w    = tid >> 6;
    const int n16  = lane & 15;
    const int quad = lane >> 4;

    __shared__ __align__(16) unsigned short Kl[2][64 * 128];   // 32768 B
    __shared__ __align__(16) unsigned short Vl[2][128 * 64];   // 32768 B
    __shared__ __align__(16) unsigned short Pl[4][16 * 72];    //  9216 B

    const size_t bT = (size_t)b * T_SEQ;
    const int qbase = qt * 64 + w * 16;
    const int k0 = chunk * 8;
    const int k1 = min(k0 + 8, qt + 1);

    const char* kbase = (const char*)(kb + bT * C_DIM);
    const char* vbase = (const char*)(vtb + (size_t)b * C_DIM * T_SEQ);

    // prologue: stage first tile (8 vmem ops/wave outstanding)
    stage_tile(kbase + (size_t)k0 * 64 * 256, vbase + (size_t)k0 * 128,
               Kl[0], Vl[0], tid, w);

    bf16x8 qfr[4];
    #pragma unroll
    for (int kk = 0; kk < 4; ++kk)
        qfr[kk] = *reinterpret_cast<const bf16x8*>(
            qb + (bT + qbase + n16) * C_DIM + kk * 32 + quad * 8);

    f32x4 o[8];
    #pragma unroll
    for (int ct = 0; ct < 8; ++ct) o[ct] = (f32x4){0.f, 0.f, 0.f, 0.f};
    float m[4], l[4];
    #pragma unroll
    for (int r = 0; r < 4; ++r) { m[r] = -INFINITY; l[r] = 0.f; }

    int cur = 0;
    for (int kt = k0; kt < k1; ++kt, cur ^= 1) {
        if (kt + 1 < k1) {
            // issue next tile into the other buffer, then wait only for the
            // CURRENT tile (the 8 newest vmem ops are the prefetch).
            stage_tile(kbase + (size_t)(kt + 1) * 64 * 256,
                       vbase + (size_t)(kt + 1) * 128,
                       Kl[cur ^ 1], Vl[cur ^ 1], tid, w);
            asm volatile("s_waitcnt vmcnt(8)" ::: "memory");
        } else {
            asm volatile("s_waitcnt vmcnt(0)" ::: "memory");
        }
        __builtin_amdgcn_s_barrier();      // all waves' current tile complete

        const unsigned short* klc = Kl[cur];
        const unsigned short* vlc = Vl[cur];

        f32x4 s[4];
        #pragma unroll
        for (int nt = 0; nt < 4; ++nt) s[nt] = (f32x4){0.f, 0.f, 0.f, 0.f};
        #pragma unroll
        for (int kk = 0; kk < 4; ++kk)
            #pragma unroll
            for (int nt = 0; nt < 4; ++nt) {
                const int rr = nt * 16 + n16;
                const int p  = (kk * 4 + quad) ^ (n16 & 7);
                bf16x8 bfr = *reinterpret_cast<const bf16x8*>(&klc[rr * 128 + p * 8]);
                s[nt] = __builtin_amdgcn_mfma_f32_16x16x32_bf16(qfr[kk], bfr, s[nt], 0, 0, 0);
            }

        if (kt == qt) {
            #pragma unroll
            for (int nt = 0; nt < 4; ++nt)
                #pragma unroll
                for (int r = 0; r < 4; ++r) {
                    int sabs = kt * 64 + nt * 16 + n16;
                    int qabs = qbase + quad * 4 + r;
                    if (sabs > qabs) s[nt][r] = -1e30f;
                }
        }

        float alpha[4];
        #pragma unroll
        for (int r = 0; r < 4; ++r) {
            float tmax = fmaxf(fmaxf(s[0][r], s[1][r]), fmaxf(s[2][r], s[3][r]));
            #pragma unroll
            for (int off = 1; off < 16; off <<= 1)
                tmax = fmaxf(tmax, __shfl_xor(tmax, off));
            float mn = fmaxf(m[r], tmax);
            alpha[r] = __expf(m[r] - mn);
            float tsum = 0.f;
            #pragma unroll
            for (int nt = 0; nt < 4; ++nt) {
                float p = __expf(s[nt][r] - mn);
                s[nt][r] = p;
                tsum += p;
            }
            #pragma unroll
            for (int off = 1; off < 16; off <<= 1)
                tsum += __shfl_xor(tsum, off);
            l[r] = l[r] * alpha[r] + tsum;
            m[r] = mn;
        }
        #pragma unroll
        for (int ct = 0; ct < 8; ++ct)
            #pragma unroll
            for (int r = 0; r < 4; ++r)
                o[ct][r] *= alpha[r];

        unsigned short* pw = Pl[w];
        #pragma unroll
        for (int nt = 0; nt < 4; ++nt)
            #pragma unroll
            for (int r = 0; r < 4; ++r)
                pw[(quad * 4 + r) * 72 + nt * 16 + n16] = f2bf(s[nt][r]);

        #pragma unroll
        for (int kk2 = 0; kk2 < 2; ++kk2) {
            bf16x8 afr = *reinterpret_cast<const bf16x8*>(
                &pw[n16 * 72 + kk2 * 32 + quad * 8]);
            #pragma unroll
            for (int ct = 0; ct < 8; ++ct) {
                const int rv = ct * 16 + n16;
                const int p  = (kk2 * 4 + quad) ^ (n16 & 7);
                bf16x8 bfr = *reinterpret_cast<const bf16x8*>(&vlc[rv * 64 + p * 8]);
                o[ct] = __builtin_amdgcn_mfma_f32_16x16x32_bf16(afr, bfr, o[ct], 0, 0, 0);
            }
        }

        // all waves done reading this buffer before next iter overwrites it;
        // drain only LDS ops — vmcnt (the prefetch) stays in flight.
        asm volatile("s_waitcnt lgkmcnt(0)" ::: "memory");
        __builtin_amdgcn_s_barrier();
    }

    if (qt < 8) {
        float* outp = out + (bT + qbase) * C_DIM;
        #pragma unroll
        for (int r = 0; r < 4; ++r) {
            float inv = 1.0f / l[r];
            #pragma unroll
            for (int ct = 0; ct < 8; ++ct)
                outp[(size_t)(quad * 4 + r) * C_DIM + ct * 16 + n16] = o[ct][r] * inv;
        }
    } else {
        const int slot = b * 72 + chunk_base(qt) + chunk;
        float* op = opart + (size_t)slot * 8192;
        #pragma unroll
        for (int r = 0; r < 4; ++r) {
            int row = w * 16 + quad * 4 + r;
            #pragma unroll
            for (int ct = 0; ct < 8; ++ct)
                op[row * 128 + ct * 16 + n16] = o[ct][r];
            if (n16 == 0)
                mlbuf[(size_t)slot * 64 + row] = make_float2(m[r], l[r]);
        }
    }
}

// ---------------------------------------------------------------------------
// merge: combine <=4 partials per (b, qt>=8). grid (24, 8), block 256.
// ---------------------------------------------------------------------------
__global__ __launch_bounds__(256) void merge_kernel(
    const float* __restrict__ opart, const float2* __restrict__ mlbuf,
    float* __restrict__ out)
{
    const int qt = 8 + blockIdx.x;
    const int b  = blockIdx.y;
    const int nch  = (qt >> 3) + 1;
    const int base = b * 72 + chunk_base(qt);
    const int row = threadIdx.x >> 2;
    const int c0  = (threadIdx.x & 3) * 32;

    float mi[4], li[4], wgt[4];
    float M = -INFINITY;
    for (int i = 0; i < nch; ++i) {
        float2 t = mlbuf[(size_t)(base + i) * 64 + row];
        mi[i] = t.x; li[i] = t.y;
        M = fmaxf(M, t.x);
    }
    float L = 0.f;
    for (int i = 0; i < nch; ++i) {
        wgt[i] = __expf(mi[i] - M);
        L += li[i] * wgt[i];
    }
    const float inv = 1.0f / L;

    float* orow = out + ((size_t)(b * T_SEQ + qt * 64 + row)) * C_DIM;
    #pragma unroll
    for (int j = 0; j < 8; ++j) {
        int col = c0 + j * 4;
        float ax = 0.f, ay = 0.f, az = 0.f, aw = 0.f;
        for (int i = 0; i < nch; ++i) {
            float4 p = *reinterpret_cast<const float4*>(
                opart + (size_t)(base + i) * 8192 + row * 128 + col);
            ax += wgt[i] * p.x; ay += wgt[i] * p.y;
            az += wgt[i] * p.z; aw += wgt[i] * p.w;
        }
        float4 r4; r4.x = ax * inv; r4.y = ay * inv; r4.z = az * inv; r4.w = aw * inv;
        *reinterpret_cast<float4*>(orow + col) = r4;
    }
}

extern "C" void kernel_launch(void* const* d_in, const int* in_sizes, int n_in,
                              void* d_out, int out_size, void* d_ws, size_t ws_size,
                              hipStream_t stream) {
    const float* x  = (const float*)d_in[0];
    const float* Wk = (const float*)d_in[1];
    const float* Wq = (const float*)d_in[2];
    const float* Wv = (const float*)d_in[3];

    unsigned short* qw  = (unsigned short*)d_ws;
    unsigned short* kw  = qw + 2097152;
    unsigned short* vw  = kw + 2097152;
    float*          opart = (float*)((char*)d_ws + OPART_OFF);
    float2*         mlb   = (float2*)((char*)d_ws + ML_OFF);

    proj_kernel<<<dim3(256, 3), 256, 0, stream>>>(x, Wk, Wq, Wv, qw, kw, vw);
    attn_kernel<<<dim3(1024), 256, 0, stream>>>(qw, kw, vw, opart, mlb, (float*)d_out);
    merge_kernel<<<dim3(24, 8), 256, 0, stream>>>(opart, mlb, (float*)d_out);
}

// Round 2
// 122.624 us; speedup vs baseline: 1.1048x; 1.0200x over previous
//
#include <hip/hip_runtime.h>

#define T_SEQ 2048
#define C_DIM 128
#define S_QK 0.08838834764831845f

typedef __attribute__((ext_vector_type(8))) short bf16x8;
typedef __attribute__((ext_vector_type(4))) float f32x4;

// ---- workspace layout (bytes) ----
// qw  bf16 [8][2048][128]            @ 0         (4,194,304)
// kw  bf16 [8][2048][128]            @ 4194304   (4,194,304)
// vw  bf16 [8][128][2048] (V^T)      @ 8388608   (4,194,304)
// Opart f32 [8*72][64][128]          @ 12582912  (18,874,368)
// ml  float2 [8*72][64]              @ 31457280  (294,912)
#define OPART_OFF 12582912UL
#define ML_OFF    31457280UL

// async global->LDS, 16B per lane; LDS dest is wave-uniform base + lane*16
#define GLOAD_LDS16(gp, lp)                                          \
    __builtin_amdgcn_global_load_lds(                                \
        (const __attribute__((address_space(1))) void*)(gp),         \
        (__attribute__((address_space(3))) void*)(lp), 16, 0, 0)

__device__ __forceinline__ unsigned short f2bf(float f) {
    union { float f; unsigned int u; } v; v.f = f;
    unsigned int r = v.u + 0x7FFFu + ((v.u >> 16) & 1u);
    return (unsigned short)(r >> 16);
}

// compact chunk-slot base within a batch, for qt>=8 (chunks of 8 key-tiles)
__device__ __forceinline__ int chunk_base(int qt) {
    int g = qt >> 3;                       // 1,2,3
    if (g == 1) return (qt - 8) * 2;
    if (g == 2) return 16 + (qt - 16) * 3;
    return 40 + (qt - 24) * 4;             // total 72 per batch
}

// ---------------------------------------------------------------------------
// proj (prep fused): one of q|k|vT = (bf16(x)) @ (bf16(W))^T.
// grid (256 row-tiles, 3), block 256.
// ---------------------------------------------------------------------------
__global__ __launch_bounds__(256) void proj_kernel(
    const float* __restrict__ x,
    const float* __restrict__ Wk, const float* __restrict__ Wq,
    const float* __restrict__ Wv,
    unsigned short* __restrict__ qo, unsigned short* __restrict__ ko,
    unsigned short* __restrict__ vto)
{
    const int rt = blockIdx.x;             // 64-row tile over B*T
    const int z  = blockIdx.y;             // 0=q, 1=k, 2=v(transposed)
    const int tid  = threadIdx.x;
    const int lane = tid & 63;
    const int w    = tid >> 6;
    const int n16  = lane & 15;
    const int quad = lane >> 4;

    __shared__ __align__(16) unsigned short Wl[128 * 136];   // 34816 B
    __shared__ __align__(16) unsigned short Xl[9216];        // 18432 B

    const float* Wsrc = (z == 0 ? Wq : z == 1 ? Wk : Wv);
    const float wscale = (z == 0) ? S_QK : 1.0f;
    #pragma unroll
    for (int i = 0; i < 16; ++i) {
        int e = (tid + i * 256) * 4;       // 16384 f32, 4 per op
        int r = e >> 7, c = e & 127;
        float4 v = *reinterpret_cast<const float4*>(Wsrc + e);
        ushort4 o4;
        o4.x = f2bf(v.x * wscale); o4.y = f2bf(v.y * wscale);
        o4.z = f2bf(v.z * wscale); o4.w = f2bf(v.w * wscale);
        *reinterpret_cast<ushort4*>(&Wl[r * 136 + c]) = o4;
    }
    const float* xrow = x + (size_t)rt * 64 * C_DIM;
    #pragma unroll
    for (int i = 0; i < 8; ++i) {
        int e = (tid + i * 256) * 4;       // 8192 f32
        int r = e >> 7, c = e & 127;
        float4 v = *reinterpret_cast<const float4*>(xrow + e);
        ushort4 o4;
        o4.x = f2bf(v.x); o4.y = f2bf(v.y);
        o4.z = f2bf(v.z); o4.w = f2bf(v.w);
        *reinterpret_cast<ushort4*>(&Xl[r * 136 + c]) = o4;
    }
    __syncthreads();

    const int arow = w * 16 + n16;
    bf16x8 afr[4];
    #pragma unroll
    for (int kk = 0; kk < 4; ++kk)
        afr[kk] = *reinterpret_cast<const bf16x8*>(&Xl[arow * 136 + kk * 32 + quad * 8]);

    f32x4 acc[8];
    #pragma unroll
    for (int nt = 0; nt < 8; ++nt) acc[nt] = (f32x4){0.f, 0.f, 0.f, 0.f};
    #pragma unroll
    for (int kk = 0; kk < 4; ++kk)
        #pragma unroll
        for (int nt = 0; nt < 8; ++nt) {
            bf16x8 bfr = *reinterpret_cast<const bf16x8*>(
                &Wl[(nt * 16 + n16) * 136 + kk * 32 + quad * 8]);
            acc[nt] = __builtin_amdgcn_mfma_f32_16x16x32_bf16(afr[kk], bfr, acc[nt], 0, 0, 0);
        }

    const int trow_base = w * 16 + quad * 4;
    __syncthreads();                       // all waves done reading Xl
    if (z < 2) {
        #pragma unroll
        for (int nt = 0; nt < 8; ++nt)
            #pragma unroll
            for (int r = 0; r < 4; ++r)
                Xl[(trow_base + r) * 136 + nt * 16 + n16] = f2bf(acc[nt][r]);
        __syncthreads();
        unsigned short* dst = (z == 0 ? qo : ko) + (size_t)rt * 64 * C_DIM;
        #pragma unroll
        for (int i = 0; i < 4; ++i) {
            int e = (tid + i * 256) * 8;
            int r = e >> 7, c = e & 127;
            *reinterpret_cast<uint4*>(dst + e) =
                *reinterpret_cast<const uint4*>(&Xl[r * 136 + c]);
        }
    } else {
        // transpose v tile: vT[d][t_local], row stride 72
        const int b  = rt >> 5;
        const int qt = rt & 31;
        #pragma unroll
        for (int nt = 0; nt < 8; ++nt)
            #pragma unroll
            for (int r = 0; r < 4; ++r)
                Xl[(nt * 16 + n16) * 72 + trow_base + r] = f2bf(acc[nt][r]);
        __syncthreads();
        unsigned short* dst = vto + (size_t)b * C_DIM * T_SEQ + (size_t)qt * 64;
        #pragma unroll
        for (int i = 0; i < 4; ++i) {
            int e = tid + i * 256;
            int d = e >> 3, cv = (e & 7) * 8;
            *reinterpret_cast<uint4*>(dst + (size_t)d * T_SEQ + cv) =
                *reinterpret_cast<const uint4*>(&Xl[d * 72 + cv]);
        }
    }
}

// ---------------------------------------------------------------------------
// attn pass 1: split-K flash attention, swapped-operand MFMA + 32-key steps.
// grid 1024 linear; b = lin&7 (batch -> XCD L2 affinity).
// LDS 37.9 KB -> 4 blocks/CU (16 waves/CU). Double-buffered K [2][32][128]
// and V^T [2][128][32] staged via global_load_lds w=16 (4 ops/thread/tile,
// steady-state wait vmcnt(4): the newest 4 are the prefetch).
// Swizzles (source-side XOR == read-side XOR, both bank-uniform 2-way):
//   K (16 chunks/row):  c ^= (r & 7)
//   V ( 4 chunks/row):  c ^= (r & 3) ^ ((r >> 2) & 3)
// Swapped QK^T: s = mfma(kfr, qfr) -> lane holds S^T[s=nt*16+quad*4+r][q=n16]
// so softmax over s is 7 in-lane fmax + 2 shfl_xor; m/l/alpha scalar per lane.
// Swapped PV: o = mfma(vfr, pfr) -> lane holds O^T[d=ct*16+quad*4+r][q=n16],
// 4 consecutive d per lane -> float4 epilogue stores.
// ---------------------------------------------------------------------------
__device__ __forceinline__ void stage_tile32(
    const char* ksb, const char* vsb,
    unsigned short* klbuf, unsigned short* vlbuf, int tid, int w)
{
    #pragma unroll
    for (int it = 0; it < 2; ++it) {                 // K: 32 rows x 16 chunks
        const int L = it * 256 + tid;
        const int r = L >> 4, c = L & 15;
        GLOAD_LDS16(ksb + r * 256 + ((c ^ (r & 7)) << 4),
                    klbuf + (size_t)(it * 256 + w * 64) * 8);
    }
    #pragma unroll
    for (int it = 0; it < 2; ++it) {                 // V^T: 128 rows x 4 chunks
        const int L = it * 256 + tid;
        const int r = L >> 2, c = L & 3;
        GLOAD_LDS16(vsb + (size_t)r * (T_SEQ * 2) +
                        ((c ^ (r & 3) ^ ((r >> 2) & 3)) << 4),
                    vlbuf + (size_t)(it * 256 + w * 64) * 8);
    }
}

__global__ __launch_bounds__(256, 4) void attn_kernel(
    const unsigned short* __restrict__ qb,
    const unsigned short* __restrict__ kb,
    const unsigned short* __restrict__ vtb,
    float* __restrict__ opart, float2* __restrict__ mlbuf,
    float* __restrict__ out)
{
    const int lin   = blockIdx.x;
    const int b     = lin & 7;             // batch -> XCD affinity
    const int rest  = lin >> 3;
    const int qt    = rest & 31;
    const int chunk = rest >> 5;
    if (chunk * 8 > qt) return;

    const int tid  = threadIdx.x;
    const int lane = tid & 63;
    const int w    = tid >> 6;
    const int n16  = lane & 15;
    const int quad = lane >> 4;

    __shared__ __align__(16) unsigned short Kl[2][32 * 128];   // 16384 B
    __shared__ __align__(16) unsigned short Vl[2][128 * 32];   // 16384 B
    __shared__ __align__(16) unsigned short Pl[4][16 * 40];    //  5120 B

    const size_t bT = (size_t)b * T_SEQ;
    const int qbase = qt * 64 + w * 16;
    const int qabs  = qbase + n16;         // this lane's q row

    // s-tile (32 keys) range for this chunk
    const int st0 = chunk * 16;
    const int st1 = min(chunk * 16 + 16, 2 * qt + 2);

    const char* kbase = (const char*)(kb + bT * C_DIM);
    const char* vbase = (const char*)(vtb + (size_t)b * C_DIM * T_SEQ);

    // prologue: stage first tile (4 vmem ops/thread outstanding)
    stage_tile32(kbase + (size_t)st0 * 8192, vbase + (size_t)st0 * 64,
                 Kl[0], Vl[0], tid, w);

    bf16x8 qfr[4];
    #pragma unroll
    for (int kk = 0; kk < 4; ++kk)
        qfr[kk] = *reinterpret_cast<const bf16x8*>(
            qb + (bT + qbase + n16) * C_DIM + kk * 32 + quad * 8);

    f32x4 o[8];
    #pragma unroll
    for (int ct = 0; ct < 8; ++ct) o[ct] = (f32x4){0.f, 0.f, 0.f, 0.f};
    float m_ = -INFINITY, l_ = 0.f;

    unsigned short* pw = Pl[w];
    const int vswz = (quad ^ (n16 & 3) ^ ((n16 >> 2) & 3)) * 8;

    int cur = 0;
    for (int st = st0; st < st1; ++st, cur ^= 1) {
        if (st + 1 < st1) {
            stage_tile32(kbase + (size_t)(st + 1) * 8192,
                         vbase + (size_t)(st + 1) * 64,
                         Kl[cur ^ 1], Vl[cur ^ 1], tid, w);
            asm volatile("s_waitcnt vmcnt(4)" ::: "memory");
        } else {
            asm volatile("s_waitcnt vmcnt(0)" ::: "memory");
        }
        __builtin_amdgcn_s_barrier();      // current tile resident in LDS

        const unsigned short* klc = Kl[cur];
        const unsigned short* vlc = Vl[cur];

        // QK^T (swapped): s[nt] holds S^T[s-rows][q=n16]
        f32x4 s[2];
        s[0] = (f32x4){0.f, 0.f, 0.f, 0.f};
        s[1] = (f32x4){0.f, 0.f, 0.f, 0.f};
        #pragma unroll
        for (int kk = 0; kk < 4; ++kk)
            #pragma unroll
            for (int nt = 0; nt < 2; ++nt) {
                bf16x8 kfr = *reinterpret_cast<const bf16x8*>(
                    &klc[(nt * 16 + n16) * 128 + (((kk * 4 + quad) ^ (n16 & 7)) * 8)]);
                s[nt] = __builtin_amdgcn_mfma_f32_16x16x32_bf16(kfr, qfr[kk], s[nt], 0, 0, 0);
            }

        if (st >= 2 * qt) {                // only the diagonal s-tiles mask
            #pragma unroll
            for (int nt = 0; nt < 2; ++nt)
                #pragma unroll
                for (int r = 0; r < 4; ++r) {
                    int sabs = st * 32 + nt * 16 + quad * 4 + r;
                    if (sabs > qabs) s[nt][r] = -1e30f;
                }
        }

        // online softmax, per-lane scalar (q = n16), reduce over quads
        float pmax = fmaxf(fmaxf(fmaxf(s[0][0], s[0][1]), fmaxf(s[0][2], s[0][3])),
                           fmaxf(fmaxf(s[1][0], s[1][1]), fmaxf(s[1][2], s[1][3])));
        pmax = fmaxf(pmax, __shfl_xor(pmax, 16));
        pmax = fmaxf(pmax, __shfl_xor(pmax, 32));
        float mn = fmaxf(m_, pmax);
        float alpha = __expf(m_ - mn);
        float tsum = 0.f;
        #pragma unroll
        for (int nt = 0; nt < 2; ++nt)
            #pragma unroll
            for (int r = 0; r < 4; ++r) {
                float p = __expf(s[nt][r] - mn);
                s[nt][r] = p;
                tsum += p;
            }
        tsum += __shfl_xor(tsum, 16);
        tsum += __shfl_xor(tsum, 32);
        l_ = l_ * alpha + tsum;
        m_ = mn;
        #pragma unroll
        for (int ct = 0; ct < 8; ++ct) {
            o[ct][0] *= alpha; o[ct][1] *= alpha;
            o[ct][2] *= alpha; o[ct][3] *= alpha;
        }

        // P^T -> LDS as P[q=n16][s_local] rows (stride 40 shorts)
        #pragma unroll
        for (int nt = 0; nt < 2; ++nt) {
            ushort4 pk;
            pk.x = f2bf(s[nt][0]); pk.y = f2bf(s[nt][1]);
            pk.z = f2bf(s[nt][2]); pk.w = f2bf(s[nt][3]);
            *reinterpret_cast<ushort4*>(&pw[n16 * 40 + nt * 16 + quad * 4]) = pk;
        }

        // PV (swapped): o[ct] += V^T-frag x P-frag
        bf16x8 pfr = *reinterpret_cast<const bf16x8*>(&pw[n16 * 40 + quad * 8]);
        #pragma unroll
        for (int ct = 0; ct < 8; ++ct) {
            bf16x8 vfr = *reinterpret_cast<const bf16x8*>(
                &vlc[(ct * 16 + n16) * 32 + vswz]);
            o[ct] = __builtin_amdgcn_mfma_f32_16x16x32_bf16(vfr, pfr, o[ct], 0, 0, 0);
        }

        // all waves done reading this buffer before next iter overwrites it;
        // vmcnt (the prefetch) stays in flight.
        asm volatile("s_waitcnt lgkmcnt(0)" ::: "memory");
        __builtin_amdgcn_s_barrier();
    }

    // epilogue: lane holds O^T[d = ct*16+quad*4+(0..3)][q = n16]
    if (qt < 8) {
        float* outp = out + (bT + qbase + n16) * C_DIM;
        const float inv = 1.0f / l_;
        #pragma unroll
        for (int ct = 0; ct < 8; ++ct) {
            float4 r4;
            r4.x = o[ct][0] * inv; r4.y = o[ct][1] * inv;
            r4.z = o[ct][2] * inv; r4.w = o[ct][3] * inv;
            *reinterpret_cast<float4*>(outp + ct * 16 + quad * 4) = r4;
        }
    } else {
        const int slot = b * 72 + chunk_base(qt) + chunk;
        float* op = opart + (size_t)slot * 8192 + (size_t)(w * 16 + n16) * 128;
        #pragma unroll
        for (int ct = 0; ct < 8; ++ct) {
            float4 r4;
            r4.x = o[ct][0]; r4.y = o[ct][1];
            r4.z = o[ct][2]; r4.w = o[ct][3];
            *reinterpret_cast<float4*>(op + ct * 16 + quad * 4) = r4;
        }
        if (quad == 0)
            mlbuf[(size_t)slot * 64 + w * 16 + n16] = make_float2(m_, l_);
    }
}

// ---------------------------------------------------------------------------
// merge: combine <=4 partials per (b, qt>=8). grid (24, 8), block 256.
// ---------------------------------------------------------------------------
__global__ __launch_bounds__(256) void merge_kernel(
    const float* __restrict__ opart, const float2* __restrict__ mlbuf,
    float* __restrict__ out)
{
    const int qt = 8 + blockIdx.x;
    const int b  = blockIdx.y;
    const int nch  = (qt >> 3) + 1;
    const int base = b * 72 + chunk_base(qt);
    const int row = threadIdx.x >> 2;
    const int c0  = (threadIdx.x & 3) * 32;

    float mi[4], li[4], wgt[4];
    float M = -INFINITY;
    for (int i = 0; i < nch; ++i) {
        float2 t = mlbuf[(size_t)(base + i) * 64 + row];
        mi[i] = t.x; li[i] = t.y;
        M = fmaxf(M, t.x);
    }
    float L = 0.f;
    for (int i = 0; i < nch; ++i) {
        wgt[i] = __expf(mi[i] - M);
        L += li[i] * wgt[i];
    }
    const float inv = 1.0f / L;

    float* orow = out + ((size_t)(b * T_SEQ + qt * 64 + row)) * C_DIM;
    #pragma unroll
    for (int j = 0; j < 8; ++j) {
        int col = c0 + j * 4;
        float ax = 0.f, ay = 0.f, az = 0.f, aw = 0.f;
        for (int i = 0; i < nch; ++i) {
            float4 p = *reinterpret_cast<const float4*>(
                opart + (size_t)(base + i) * 8192 + row * 128 + col);
            ax += wgt[i] * p.x; ay += wgt[i] * p.y;
            az += wgt[i] * p.z; aw += wgt[i] * p.w;
        }
        float4 r4; r4.x = ax * inv; r4.y = ay * inv; r4.z = az * inv; r4.w = aw * inv;
        *reinterpret_cast<float4*>(orow + col) = r4;
    }
}

extern "C" void kernel_launch(void* const* d_in, const int* in_sizes, int n_in,
                              void* d_out, int out_size, void* d_ws, size_t ws_size,
                              hipStream_t stream) {
    const float* x  = (const float*)d_in[0];
    const float* Wk = (const float*)d_in[1];
    const float* Wq = (const float*)d_in[2];
    const float* Wv = (const float*)d_in[3];

    unsigned short* qw  = (unsigned short*)d_ws;
    unsigned short* kw  = qw + 2097152;
    unsigned short* vw  = kw + 2097152;
    float*          opart = (float*)((char*)d_ws + OPART_OFF);
    float2*         mlb   = (float2*)((char*)d_ws + ML_OFF);

    proj_kernel<<<dim3(256, 3), 256, 0, stream>>>(x, Wk, Wq, Wv, qw, kw, vw);
    attn_kernel<<<dim3(1024), 256, 0, stream>>>(qw, kw, vw, opart, mlb, (float*)d_out);
    merge_kernel<<<dim3(24, 8), 256, 0, stream>>>(opart, mlb, (float*)d_out);
}